// Round 18
// baseline (45.173 us; speedup 1.0000x reference)
//
#include <hip/hip_runtime.h>
#include <math.h>

#define E 8
#define DF 512
#define DE 128
#define H 8
#define S 64
#define GH 16
#define HD 16
#define B 2
#define NTOK 1024
#define QT 4          // query chunks per (b,e,h) in k_attn
#define KMAX 256      // staged key capacity (c ~ Binom(1024,1/8) ~ 128 +/- 11)

__device__ __forceinline__ float wave_sum(float v) {
#pragma unroll
    for (int m = 32; m; m >>= 1) v += __shfl_xor(v, m, 64);
    return v;
}

// ---- kernel 1: prep (R9-proven) ----
// bid 0-7: expert lists | 8-23: WfT | 24-71: WqT/WkT/WvT | 72-583: LN+gate -> fg
__global__ __launch_bounds__(256) void k_prep(
    const float* __restrict__ Wq, const float* __restrict__ Wk,
    const float* __restrict__ Wv, const float* __restrict__ Wf,
    const float* __restrict__ fp, const float* __restrict__ x,
    const float* __restrict__ lnw, const float* __restrict__ lnb,
    const float* __restrict__ alpha,
    const float* __restrict__ Wg1, const float* __restrict__ bg1,
    const float* __restrict__ Wg2, const float* __restrict__ bg2,
    float* __restrict__ WfT, float* __restrict__ WqT, float* __restrict__ WkT,
    float* __restrict__ WvT, unsigned* __restrict__ cnt,
    unsigned* __restrict__ lst, float* __restrict__ fg) {
    __shared__ __align__(16) float sh[64][65];
    int bid = blockIdx.x, tid = threadIdx.x;
    if (bid < 8) {                        // expert token lists (1 wave)
        if (tid >= 64) return;
        int e = bid, l = tid;
        unsigned c = 0;
        for (int base = 0; base < NTOK; base += 64) {
            int n = base + l;
            int ee = (int)(fp[n] * 8.0f);
            ee = ee > 7 ? 7 : ee;
            bool in = (ee == e);
            unsigned long long m = __ballot(in);
            unsigned pos = (unsigned)__popcll(m & ((1ull << l) - 1ull));
            if (in) lst[e * NTOK + c + pos] = (unsigned)n;
            c += (unsigned)__popcll(m);
        }
        if (l == 0) cnt[e] = c;
        return;
    }
    if (bid < 72) {                       // transposes
        const float* in;
        float* out;
        int istride, ostride;
        if (bid < 24) {                   // Wf [512][128] -> WfT [128][512]
            int i = bid - 8, rt = i >> 1, ct2 = i & 1;
            in = Wf + (size_t)rt * 64 * DE + ct2 * 64;
            out = WfT + (size_t)ct2 * 64 * DF + rt * 64;
            istride = DE; ostride = DF;
        } else {                          // Wq/Wk/Wv [128][64]/expert -> [64][128]
            int bb = bid - 24;
            int m = bb >> 4, e = (bb >> 1) & 7, dt = bb & 1;
            const float* W = (m == 0) ? Wq : (m == 1) ? Wk : Wv;
            float* WT      = (m == 0) ? WqT : (m == 1) ? WkT : WvT;
            in = W + (size_t)e * DE * S + (size_t)dt * 64 * S;
            out = WT + (size_t)e * S * DE + dt * 64;
            istride = S; ostride = DE;
        }
        int c = tid & 63, r0 = tid >> 6;
        for (int r = r0; r < 64; r += 4) sh[r][c] = in[(size_t)r * istride + c];
        __syncthreads();
        for (int cc = r0; cc < 64; cc += 4)
            out[(size_t)cc * ostride + c] = sh[c][cc];
        return;
    }
    // ---- LN + gate, 1 token per wave ----
    float (*fsh)[64] = (float(*)[64])sh;
    int wave = tid >> 6, lane = tid & 63;
    int t = (bid - 72) * 4 + wave;        // 0..2047
    int n = t & (NTOK - 1);
    const float* xr = x + (size_t)t * DF;
    float4 a  = *(const float4*)(xr + lane * 8);
    float4 b4 = *(const float4*)(xr + lane * 8 + 4);
    float s  = a.x + a.y + a.z + a.w + b4.x + b4.y + b4.z + b4.w;
    float ss = a.x*a.x + a.y*a.y + a.z*a.z + a.w*a.w
             + b4.x*b4.x + b4.y*b4.y + b4.z*b4.z + b4.w*b4.w;
    s = wave_sum(s);
    ss = wave_sum(ss);
    float mu  = s * (1.0f / DF);
    float var = ss * (1.0f / DF) - mu * mu;
    float rs  = rsqrtf(var + 1e-5f);
    int e = (int)(fp[n] * 8.0f);
    e = e > 7 ? 7 : e;
    float f = (xr[e * 64 + lane] - mu) * rs * lnw[e * 64 + lane]
            + lnb[e * 64 + lane];
    fsh[wave][lane] = f;
    __syncthreads();
    int hh = lane & 15, sb = (lane >> 4) * 16;
    const float* wg1 = Wg1 + ((size_t)e * GH + hh) * S;
    float g1p = 0.f;
#pragma unroll
    for (int si = 0; si < 16; si++) g1p += fsh[wave][sb + si] * wg1[sb + si];
    g1p += __shfl_xor(g1p, 16, 64);
    g1p += __shfl_xor(g1p, 32, 64);
    float g1 = g1p + bg1[e * GH + hh];
    g1 = 0.5f * g1 * (1.0f + erff(g1 * 0.70710678118654752f));
    float part = g1 * Wg2[e * GH + hh];
    part += __shfl_xor(part, 1, 64);
    part += __shfl_xor(part, 2, 64);
    part += __shfl_xor(part, 4, 64);
    part += __shfl_xor(part, 8, 64);
    float g2 = part + bg2[e];
    float gate = 1.0f / (1.0f + __expf(-g2));
    float aw = 1.0f / (1.0f + __expf(-alpha[e]));
    float gm = gate * aw + (1.0f - aw);
    fg[(size_t)t * S + lane] = f * gm;
}

// ---- kernel 2: QKV as k_proj-style GEMM: 8 same-expert tokens/block ----
// 384 thr = (mat, dcol); one coalesced weight load feeds 8 FMA.
__global__ __launch_bounds__(384) void k_qkv8(
    const float* __restrict__ fg,
    const float* __restrict__ WqT, const float* __restrict__ WkT,
    const float* __restrict__ WvT,
    const unsigned* __restrict__ cnt, const unsigned* __restrict__ lst,
    float* __restrict__ Q, float* __restrict__ K, float* __restrict__ V) {
    __shared__ float fr[8][68];           // 2.1 KB (padded rows)
    __shared__ int toks[8];
    int bid = blockIdx.x;                 // b*(E*16) + e*16 + ci
    int ci = bid & 15, e = (bid >> 4) & 7, b = bid >> 7;
    int c = (int)cnt[e];
    if (ci * 8 >= c) return;              // block-uniform
    const unsigned* L = lst + e * NTOK;
    int tid = threadIdx.x;
    int mat = tid / 128, dcol = tid & 127;
    const float* WT = (mat == 0) ? WqT : (mat == 1) ? WkT : WvT;
    const float* wp = WT + (size_t)e * S * DE + dcol;
    float* Ob = (mat == 0) ? Q : (mat == 1) ? K : V;

    for (int base = ci * 8; base < c; base += 128) {   // block-uniform trips
        if (tid < 8) toks[tid] = (int)L[min(base + tid, c - 1)];
        __syncthreads();
        if (tid < 128) {
            int tok = tid >> 4, p4 = tid & 15;
            float4 v = ((const float4*)(fg + (size_t)(b * NTOK + toks[tok]) * S))[p4];
            *(float4*)&fr[tok][p4 * 4] = v;
        }
        __syncthreads();
        float acc[8];
#pragma unroll
        for (int tk = 0; tk < 8; tk++) acc[tk] = 0.f;
#pragma unroll 8
        for (int s = 0; s < 64; s++) {
            float w = wp[(size_t)s * DE];
#pragma unroll
            for (int tk = 0; tk < 8; tk++) acc[tk] += fr[tk][s] * w;
        }
#pragma unroll
        for (int tk = 0; tk < 8; tk++) {
            if (base + tk < c)
                Ob[(size_t)(b * NTOK + toks[tk]) * DE + dcol] = acc[tk];
        }
        __syncthreads();                  // fr/toks reuse
    }
}

// ---- kernel 3: block-diagonal flash attention (R5-proven, defer-max) ----
__global__ __launch_bounds__(256) void k_attn(
    const float* __restrict__ Q, const float* __restrict__ K,
    const float* __restrict__ V, const unsigned* __restrict__ cnt,
    const unsigned* __restrict__ lst, const float* __restrict__ temp,
    float* __restrict__ F) {
    __shared__ float Ksh[KMAX][HD];       // 16 KB
    __shared__ float Vsh[KMAX][HD];       // 16 KB
    __shared__ float part[4][64][18];     // 18 KB
    int idx = blockIdx.x;                 // beh*QT + qt
    int qt = idx & (QT - 1);
    int beh = idx / QT;
    int b = beh >> 6;
    int e = (beh >> 3) & 7;
    int h = beh & 7;
    int c = (int)cnt[e];
    int qbase0 = qt * 64;
    if (qbase0 >= c) return;              // uniform per block
    int cs = c < KMAX ? c : KMAX;
    const unsigned* L = lst + e * NTOK;
    float inv_scale = 1.0f / (4.0f * fabsf(temp[0]));

    for (int j = threadIdx.x; j < cs * 4; j += 256) {
        int i = j >> 2, comp = j & 3;
        int nk = (int)L[i];
        size_t rb = (size_t)(b * NTOK + nk) * DE + h * HD;
        ((float4*)Ksh[i])[comp] = ((const float4*)(K + rb))[comp];
        ((float4*)Vsh[i])[comp] = ((const float4*)(V + rb))[comp];
    }
    __syncthreads();

    int wave = threadIdx.x >> 6;
    int lane = threadIdx.x & 63;
    int ck = (c + 3) >> 2;
    int k0 = wave * ck;
    int k1 = min(c, k0 + ck);

    for (int qb = qbase0; qb < c; qb += QT * 64) {
        int qi = qb + lane;
        bool valid = qi < c;
        int nq = (int)L[valid ? qi : c - 1];
        const float* qp = Q + ((size_t)(b * NTOK + nq) * DE + h * HD);
        float4 q0 = ((const float4*)qp)[0];
        float4 q1 = ((const float4*)qp)[1];
        float4 q2 = ((const float4*)qp)[2];
        float4 q3 = ((const float4*)qp)[3];
        q0.x *= inv_scale; q0.y *= inv_scale; q0.z *= inv_scale; q0.w *= inv_scale;
        q1.x *= inv_scale; q1.y *= inv_scale; q1.z *= inv_scale; q1.w *= inv_scale;
        q2.x *= inv_scale; q2.y *= inv_scale; q2.z *= inv_scale; q2.w *= inv_scale;
        q3.x *= inv_scale; q3.y *= inv_scale; q3.z *= inv_scale; q3.w *= inv_scale;

        float m = -INFINITY, l = 0.f;
        float4 a0 = {0,0,0,0}, a1 = {0,0,0,0}, a2 = {0,0,0,0}, a3 = {0,0,0,0};

        int kls = min(k1, cs);
        for (int i = k0; i < kls; i++) {
            float4 kk0 = ((const float4*)Ksh[i])[0];
            float4 kk1 = ((const float4*)Ksh[i])[1];
            float4 kk2 = ((const float4*)Ksh[i])[2];
            float4 kk3 = ((const float4*)Ksh[i])[3];
            float s = q0.x*kk0.x + q0.y*kk0.y + q0.z*kk0.z + q0.w*kk0.w
                    + q1.x*kk1.x + q1.y*kk1.y + q1.z*kk1.z + q1.w*kk1.w
                    + q2.x*kk2.x + q2.y*kk2.y + q2.z*kk2.z + q2.w*kk2.w
                    + q3.x*kk3.x + q3.y*kk3.y + q3.z*kk3.z + q3.w*kk3.w;
            if (__any(s - m > 8.0f)) {
                float mn = fmaxf(m, s);
                float r = __expf(m - mn);
                l *= r;
                a0.x*=r; a0.y*=r; a0.z*=r; a0.w*=r;
                a1.x*=r; a1.y*=r; a1.z*=r; a1.w*=r;
                a2.x*=r; a2.y*=r; a2.z*=r; a2.w*=r;
                a3.x*=r; a3.y*=r; a3.z*=r; a3.w*=r;
                m = mn;
            }
            float p = __expf(s - m);
            l += p;
            float4 v0 = ((const float4*)Vsh[i])[0];
            float4 v1 = ((const float4*)Vsh[i])[1];
            float4 v2 = ((const float4*)Vsh[i])[2];
            float4 v3 = ((const float4*)Vsh[i])[3];
            a0.x += p*v0.x; a0.y += p*v0.y; a0.z += p*v0.z; a0.w += p*v0.w;
            a1.x += p*v1.x; a1.y += p*v1.y; a1.z += p*v1.z; a1.w += p*v1.w;
            a2.x += p*v2.x; a2.y += p*v2.y; a2.z += p*v2.z; a2.w += p*v2.w;
            a3.x += p*v3.x; a3.y += p*v3.y; a3.z += p*v3.z; a3.w += p*v3.w;
        }
        for (int i = max(k0, cs); i < k1; i++) {   // global tail (never normally)
            int nk = (int)L[i];
            size_t rb = (size_t)(b * NTOK + nk) * DE + h * HD;
            const float* kp = K + rb;
            float s = 0.f;
            s += q0.x*kp[0] + q0.y*kp[1] + q0.z*kp[2] + q0.w*kp[3];
            s += q1.x*kp[4] + q1.y*kp[5] + q1.z*kp[6] + q1.w*kp[7];
            s += q2.x*kp[8] + q2.y*kp[9] + q2.z*kp[10] + q2.w*kp[11];
            s += q3.x*kp[12] + q3.y*kp[13] + q3.z*kp[14] + q3.w*kp[15];
            if (__any(s - m > 8.0f)) {
                float mn = fmaxf(m, s);
                float r = __expf(m - mn);
                l *= r;
                a0.x*=r; a0.y*=r; a0.z*=r; a0.w*=r;
                a1.x*=r; a1.y*=r; a1.z*=r; a1.w*=r;
                a2.x*=r; a2.y*=r; a2.z*=r; a2.w*=r;
                a3.x*=r; a3.y*=r; a3.z*=r; a3.w*=r;
                m = mn;
            }
            float p = __expf(s - m);
            l += p;
            const float* vp = V + rb;
            a0.x += p*vp[0];  a0.y += p*vp[1];  a0.z += p*vp[2];  a0.w += p*vp[3];
            a1.x += p*vp[4];  a1.y += p*vp[5];  a1.z += p*vp[6];  a1.w += p*vp[7];
            a2.x += p*vp[8];  a2.y += p*vp[9];  a2.z += p*vp[10]; a2.w += p*vp[11];
            a3.x += p*vp[12]; a3.y += p*vp[13]; a3.z += p*vp[14]; a3.w += p*vp[15];
        }

        float* pp = part[wave][lane];
        pp[0] = m; pp[1] = l;
        pp[2]  = a0.x; pp[3]  = a0.y; pp[4]  = a0.z; pp[5]  = a0.w;
        pp[6]  = a1.x; pp[7]  = a1.y; pp[8]  = a1.z; pp[9]  = a1.w;
        pp[10] = a2.x; pp[11] = a2.y; pp[12] = a2.z; pp[13] = a2.w;
        pp[14] = a3.x; pp[15] = a3.y; pp[16] = a3.z; pp[17] = a3.w;
        __syncthreads();

        if (wave == 0) {
            float M = part[0][lane][0];
            M = fmaxf(M, part[1][lane][0]);
            M = fmaxf(M, part[2][lane][0]);
            M = fmaxf(M, part[3][lane][0]);
            float Lt = 0.f;
            float o[16];
#pragma unroll
            for (int j = 0; j < 16; j++) o[j] = 0.f;
#pragma unroll
            for (int w = 0; w < 4; w++) {
                const float* qq = part[w][lane];
                float r = __expf(qq[0] - M);
                Lt += qq[1] * r;
#pragma unroll
                for (int j = 0; j < 16; j++) o[j] += qq[2 + j] * r;
            }
            if (valid) {
                float il = 1.0f / Lt;
                float* op = F + ((size_t)(b * NTOK + nq) * DE + h * HD);
#pragma unroll
                for (int j = 0; j < 4; j++)
                    ((float4*)op)[j] = make_float4(o[4*j]*il, o[4*j+1]*il,
                                                   o[4*j+2]*il, o[4*j+3]*il);
            }
        }
        __syncthreads();
    }
}

// ---- kernel 4: proj (coalesced WfT) + bias + residual, 8 tokens/block, k-split ----
__global__ __launch_bounds__(512) void k_proj(
    const float* __restrict__ x, const float* __restrict__ F,
    const float* __restrict__ WfT, const float* __restrict__ bf,
    float* __restrict__ out) {
    __shared__ float fr[8][DE];           // 4 KB
    __shared__ float pp[8][DF];           // 16 KB
    int t0 = blockIdx.x * 8;
    int tid = threadIdx.x;
    if (tid < 256) ((float4*)fr)[tid] = ((const float4*)(F + (size_t)t0 * DE))[tid];
    __syncthreads();
    int kh = tid >> 8, tt = tid & 255;
    float acc0[8], acc1[8];
#pragma unroll
    for (int tk = 0; tk < 8; tk++) { acc0[tk] = 0.f; acc1[tk] = 0.f; }
    int kb = kh * 64;
#pragma unroll 4
    for (int k = kb; k < kb + 64; k++) {
        float w0 = WfT[(size_t)k * DF + tt];
        float w1 = WfT[(size_t)k * DF + tt + 256];
#pragma unroll
        for (int tk = 0; tk < 8; tk++) {
            float fv = fr[tk][k];
            acc0[tk] += fv * w0;
            acc1[tk] += fv * w1;
        }
    }
    if (kh == 1) {
#pragma unroll
        for (int tk = 0; tk < 8; tk++) {
            pp[tk][tt]       = acc0[tk];
            pp[tk][tt + 256] = acc1[tk];
        }
    }
    __syncthreads();
    if (kh == 0) {
        float b0 = bf[tt], b1 = bf[tt + 256];
#pragma unroll
        for (int tk = 0; tk < 8; tk++) {
            size_t rb = (size_t)(t0 + tk) * DF;
            out[rb + tt]       = x[rb + tt]       + b0 + acc0[tk] + pp[tk][tt];
            out[rb + tt + 256] = x[rb + tt + 256] + b1 + acc1[tk] + pp[tk][tt + 256];
        }
    }
}

extern "C" void kernel_launch(void* const* d_in, const int* in_sizes, int n_in,
                              void* d_out, int out_size, void* d_ws, size_t ws_size,
                              hipStream_t stream) {
    (void)in_sizes; (void)n_in; (void)out_size; (void)ws_size;
    const float* x     = (const float*)d_in[0];
    const float* fp    = (const float*)d_in[1];
    const float* lnw   = (const float*)d_in[2];
    const float* lnb   = (const float*)d_in[3];
    const float* alpha = (const float*)d_in[4];
    const float* Wg1   = (const float*)d_in[5];
    const float* bg1   = (const float*)d_in[6];
    const float* Wg2   = (const float*)d_in[7];
    const float* bg2   = (const float*)d_in[8];
    const float* Wq    = (const float*)d_in[9];
    const float* Wk    = (const float*)d_in[10];
    const float* Wv    = (const float*)d_in[11];
    const float* temp  = (const float*)d_in[12];
    const float* Wf    = (const float*)d_in[13];
    const float* bf    = (const float*)d_in[14];
    float* out = (float*)d_out;

    char* ws = (char*)d_ws;
    unsigned* cnt = (unsigned*)ws;                     // 1 KB
    unsigned* lst = (unsigned*)(ws + 1024);            // 32 KB
    float* fg  = (float*)(ws + 65536);                 // 512 KB
    float* Qb  = fg + (size_t)B * NTOK * S;            // 1 MB each
    float* Kb  = Qb + (size_t)B * NTOK * DE;
    float* Vb  = Kb + (size_t)B * NTOK * DE;
    float* Fb  = Vb + (size_t)B * NTOK * DE;
    float* WfT = Fb + (size_t)B * NTOK * DE;           // 256 KB
    float* WqT = WfT + (size_t)DE * DF;                // 256 KB each
    float* WkT = WqT + (size_t)E * S * DE;
    float* WvT = WkT + (size_t)E * S * DE;

    hipLaunchKernelGGL(k_prep, dim3(584), dim3(256), 0, stream,
                       Wq, Wk, Wv, Wf, fp, x, lnw, lnb, alpha, Wg1, bg1, Wg2, bg2,
                       WfT, WqT, WkT, WvT, cnt, lst, fg);
    hipLaunchKernelGGL(k_qkv8, dim3(B * E * 16), dim3(384), 0, stream,
                       fg, WqT, WkT, WvT, cnt, lst, Qb, Kb, Vb);
    hipLaunchKernelGGL(k_attn, dim3(B * E * H * QT), dim3(256), 0, stream,
                       Qb, Kb, Vb, cnt, lst, temp, Fb);
    hipLaunchKernelGGL(k_proj, dim3(B * NTOK / 8), dim3(512), 0, stream,
                       x, Fb, WfT, bf, out);
}